// Round 1
// baseline (771.174 us; speedup 1.0000x reference)
//
#include <hip/hip_runtime.h>

#define E 1024
#define HH 64
#define BB 4
#define SS 2048
#define BS (BB*SS)   // 8192 rows

// ---------- helpers ----------
__device__ inline unsigned short f2bf(float f) {
    unsigned int u = __float_as_uint(f);
    unsigned int r = (u + 0x7FFFu + ((u >> 16) & 1u)) >> 16;   // round-to-nearest-even
    return (unsigned short)r;
}
__device__ inline float bf2f(unsigned short h) {
    return __uint_as_float(((unsigned int)h) << 16);
}

// ---------- Kernel 1: LayerNorm (fp32 in -> bf16 out) ----------
// one block per row, 256 threads x 4 floats
__global__ __launch_bounds__(256) void ln_kernel(const float* __restrict__ x,
        const float* __restrict__ gamma, const float* __restrict__ beta,
        unsigned short* __restrict__ xn) {
    const int row = blockIdx.x;
    const int tid = threadIdx.x;
    const float4 v = *(const float4*)(x + (size_t)row * E + tid * 4);
    float s  = v.x + v.y + v.z + v.w;
    float sq = v.x*v.x + v.y*v.y + v.z*v.z + v.w*v.w;
    #pragma unroll
    for (int off = 32; off > 0; off >>= 1) {
        s  += __shfl_down(s,  off);
        sq += __shfl_down(sq, off);
    }
    __shared__ float red[8];
    const int wave = tid >> 6, lane = tid & 63;
    if (lane == 0) { red[wave] = s; red[4 + wave] = sq; }
    __syncthreads();
    const float fs = red[0] + red[1] + red[2] + red[3];
    const float fq = red[4] + red[5] + red[6] + red[7];
    const float mean = fs * (1.0f / E);
    const float var  = fq * (1.0f / E) - mean * mean;
    const float rstd = rsqrtf(var + 1e-5f);
    const float4 g  = *(const float4*)(gamma + tid * 4);
    const float4 bt = *(const float4*)(beta  + tid * 4);
    ushort4 o;
    o.x = f2bf((v.x - mean) * rstd * g.x + bt.x);
    o.y = f2bf((v.y - mean) * rstd * g.y + bt.y);
    o.z = f2bf((v.z - mean) * rstd * g.z + bt.z);
    o.w = f2bf((v.w - mean) * rstd * g.w + bt.w);
    *(ushort4*)(xn + (size_t)row * E + tid * 4) = o;
}

// ---------- Kernel 2: QKV projection ----------
// A = xn [8192 x 1024] bf16, W = [192 x 1024] fp32 (q|k|v rows, each stored W[h][e])
// out q/k/v [8192 x 64] fp32.  Block: 32 rows x 96 cols, 512 blocks.
__global__ __launch_bounds__(256) void qkv_kernel(const unsigned short* __restrict__ xn,
        const float* __restrict__ Wq, const float* __restrict__ Wk, const float* __restrict__ Wv,
        float* __restrict__ qb, float* __restrict__ kb, float* __restrict__ vb) {
    const int mb   = blockIdx.x >> 1;     // 0..255
    const int half = blockIdx.x & 1;      // col half: 0 -> 0..95, 1 -> 96..191
    const int rowBase = mb * 32;
    const int t  = threadIdx.x;
    const int tr = t >> 5;                // 0..7 -> rows tr*4 .. tr*4+3
    const int tc = t & 31;                // cols tc, tc+32, tc+64 (local)

    __shared__ float xs[32][65];          // 8.3 KB  (pitch 65: conflict-free)
    __shared__ float wl[96][66];          // 25.3 KB (pitch 66: 2-way = free)

    float acc[4][3] = {};

    for (int kc = 0; kc < E; kc += 64) {
        // stage xs: 32 rows x 64 k, bf16 -> fp32
        {
            const int r  = t >> 3;
            const int k0 = (t & 7) * 8;
            const uint4 raw = *(const uint4*)(xn + (size_t)(rowBase + r) * E + kc + k0);
            const unsigned int w[4] = {raw.x, raw.y, raw.z, raw.w};
            #pragma unroll
            for (int i = 0; i < 4; ++i) {
                xs[r][k0 + 2*i]     = __uint_as_float((w[i] & 0xFFFFu) << 16);
                xs[r][k0 + 2*i + 1] = __uint_as_float(w[i] & 0xFFFF0000u);
            }
        }
        // stage wl: 96 cols x 64 k
        #pragma unroll
        for (int i = 0; i < 6; ++i) {
            const int f4 = i * 256 + t;         // 0..1535 float4 slots
            const int cl = f4 >> 4;             // 0..95
            const int k4 = (f4 & 15) * 4;
            const int cg = half * 96 + cl;
            const float* src = (cg < 64)  ? (Wq + (size_t)cg * E)
                             : (cg < 128) ? (Wk + (size_t)(cg - 64) * E)
                                          : (Wv + (size_t)(cg - 128) * E);
            const float4 w4 = *(const float4*)(src + kc + k4);
            wl[cl][k4 + 0] = w4.x; wl[cl][k4 + 1] = w4.y;
            wl[cl][k4 + 2] = w4.z; wl[cl][k4 + 3] = w4.w;
        }
        __syncthreads();
        #pragma unroll 8
        for (int kk = 0; kk < 64; ++kk) {
            const float a0 = xs[tr*4 + 0][kk];
            const float a1 = xs[tr*4 + 1][kk];
            const float a2 = xs[tr*4 + 2][kk];
            const float a3 = xs[tr*4 + 3][kk];
            const float b0 = wl[tc][kk];
            const float b1 = wl[tc + 32][kk];
            const float b2 = wl[tc + 64][kk];
            acc[0][0] += a0*b0; acc[0][1] += a0*b1; acc[0][2] += a0*b2;
            acc[1][0] += a1*b0; acc[1][1] += a1*b1; acc[1][2] += a1*b2;
            acc[2][0] += a2*b0; acc[2][1] += a2*b1; acc[2][2] += a2*b2;
            acc[3][0] += a3*b0; acc[3][1] += a3*b1; acc[3][2] += a3*b2;
        }
        __syncthreads();
    }

    #pragma unroll
    for (int i = 0; i < 4; ++i) {
        const size_t row = rowBase + tr * 4 + i;
        #pragma unroll
        for (int j = 0; j < 3; ++j) {
            const int cg = half * 96 + tc + 32 * j;
            const float val = acc[i][j];
            if (cg < 64)        qb[row * HH + cg]         = val;
            else if (cg < 128)  kb[row * HH + (cg - 64)]  = val;
            else                vb[row * HH + (cg - 128)] = val;
        }
    }
}

// ---------- Kernel 3: causal flash attention ----------
// Block = 4 consecutive queries (4 waves, 1 query/wave) of one batch.
// K tile (64 keys) staged transposed in LDS; V read coalesced from global (L1-shared).
__global__ __launch_bounds__(256) void attn_kernel(const float* __restrict__ Q,
        const float* __restrict__ K, const float* __restrict__ V,
        float* __restrict__ out) {
    const int b    = blockIdx.x >> 9;          // 512 blocks per batch
    const int q0   = (blockIdx.x & 511) * 4;
    const int t    = threadIdx.x;
    const int wave = t >> 6, lane = t & 63;
    const int qi   = q0 + wave;

    __shared__ float KT[64 * 65];              // KT[h*65 + key], conflict-free reads
    __shared__ float sQ[4 * 64];

    // fold 1/sqrt(64) and log2(e) into q so we can use exp2 everywhere
    const float scale = 0.18033688011112042f;  // log2(e)/8
    const float qv = Q[((size_t)b * SS + qi) * HH + lane] * scale;
    sQ[wave * 64 + lane] = qv;
    __syncthreads();

    float o = 0.f, m = -INFINITY, denom = 0.f;
    const int ntiles = (q0 + 67) >> 6;         // tiles covering keys 0..q0+3

    for (int tile = 0; tile < ntiles; ++tile) {
        const int kt = tile << 6;
        // stage K tile transposed (rows clamped; OOB keys are masked later)
        {
            const int r  = t >> 2;             // key 0..63
            const int qq = t & 3;
            const int rowi = min(kt + r, SS - 1);
            const float* src = K + ((size_t)b * SS + rowi) * HH + qq * 16;
            #pragma unroll
            for (int i4 = 0; i4 < 4; ++i4) {
                const float4 w4 = *(const float4*)(src + i4 * 4);
                const int c = qq * 16 + i4 * 4;
                KT[(c + 0) * 65 + r] = w4.x;
                KT[(c + 1) * 65 + r] = w4.y;
                KT[(c + 2) * 65 + r] = w4.z;
                KT[(c + 3) * 65 + r] = w4.w;
            }
        }
        __syncthreads();

        // scores: lane 'l' owns key kt+l
        float s = 0.f;
        #pragma unroll 16
        for (int h = 0; h < 64; ++h)
            s += sQ[wave * 64 + h] * KT[h * 65 + lane];
        s = (kt + lane <= qi) ? s : -INFINITY;

        // online softmax (base-2 domain)
        float tm = s;
        #pragma unroll
        for (int off = 32; off > 0; off >>= 1)
            tm = fmaxf(tm, __shfl_xor(tm, off));
        const float newm  = fmaxf(m, tm);
        const float alpha = __builtin_amdgcn_exp2f(m - newm);   // first tile: exp2(-inf)=0
        const float p     = __builtin_amdgcn_exp2f(s - newm);
        float ps = p;
        #pragma unroll
        for (int off = 32; off > 0; off >>= 1)
            ps += __shfl_xor(ps, off);
        o *= alpha;
        denom = denom * alpha + ps;
        m = newm;

        // PV: coalesced global V reads, wave-uniform loop bound
        const int jmax = min(64, qi - kt + 1);
        const float* vbase = V + ((size_t)b * SS + kt) * HH + lane;
        #pragma unroll 4
        for (int j = 0; j < jmax; ++j) {
            const float pj = __shfl(p, j);
            o += pj * vbase[(size_t)j * HH];
        }
        __syncthreads();   // before restaging KT
    }
    out[((size_t)b * SS + qi) * HH + lane] = o / denom;
}

// ---------- launch ----------
extern "C" void kernel_launch(void* const* d_in, const int* in_sizes, int n_in,
                              void* d_out, int out_size, void* d_ws, size_t ws_size,
                              hipStream_t stream) {
    const float* x     = (const float*)d_in[0];
    const float* gamma = (const float*)d_in[1];
    const float* beta  = (const float*)d_in[2];
    const float* Wq    = (const float*)d_in[3];
    const float* Wk    = (const float*)d_in[4];
    const float* Wv    = (const float*)d_in[5];
    float* out = (float*)d_out;

    // ws layout: xn bf16 (16 MB) | q fp32 (2 MB) | k (2 MB) | v (2 MB)
    unsigned short* xn = (unsigned short*)d_ws;
    float* qb = (float*)((char*)d_ws + (size_t)BS * E * sizeof(unsigned short));
    float* kb = qb + (size_t)BS * HH;
    float* vb = kb + (size_t)BS * HH;

    ln_kernel  <<<BS,        256, 0, stream>>>(x, gamma, beta, xn);
    qkv_kernel <<<512,       256, 0, stream>>>(xn, Wq, Wk, Wv, qb, kb, vb);
    attn_kernel<<<BB*SS/4,   256, 0, stream>>>(qb, kb, vb, out);
}

// Round 2
// 158.621 us; speedup vs baseline: 4.8617x; 4.8617x over previous
//
#include <hip/hip_runtime.h>

#define E 1024
#define HH 64
#define BB 4
#define SS 2048
#define BS (BB*SS)   // 8192 rows

typedef unsigned short u16;
typedef short bf16x8 __attribute__((ext_vector_type(8)));
typedef float f32x4 __attribute__((ext_vector_type(4)));

#define LOG2E_O8 0.18033688011112042f   // log2(e)/8 : folds 1/sqrt(64) + exp2 domain

__device__ inline u16 f2bf(float f) {
    unsigned int u = __float_as_uint(f);
    unsigned int r = (u + 0x7FFFu + ((u >> 16) & 1u)) >> 16;   // RNE
    return (u16)r;
}

// ---------- Kernel 1: LayerNorm, wave-per-row, fp32 -> bf16 ----------
__global__ __launch_bounds__(256) void ln_kernel(const float* __restrict__ x,
        const float* __restrict__ gamma, const float* __restrict__ beta,
        u16* __restrict__ xn) {
    const int w = threadIdx.x >> 6, lane = threadIdx.x & 63;
    const size_t row = (size_t)blockIdx.x * 4 + w;
    const float4* xr = (const float4*)(x + row * E);
    float4 v[4];
    #pragma unroll
    for (int i = 0; i < 4; ++i) v[i] = xr[lane + 64 * i];
    float s = 0.f, sq = 0.f;
    #pragma unroll
    for (int i = 0; i < 4; ++i) {
        s  += v[i].x + v[i].y + v[i].z + v[i].w;
        sq += v[i].x*v[i].x + v[i].y*v[i].y + v[i].z*v[i].z + v[i].w*v[i].w;
    }
    #pragma unroll
    for (int off = 32; off > 0; off >>= 1) {
        s  += __shfl_xor(s,  off);
        sq += __shfl_xor(sq, off);
    }
    const float mean = s * (1.0f / E);
    const float var  = sq * (1.0f / E) - mean * mean;
    const float rstd = rsqrtf(var + 1e-5f);
    const float4* gr = (const float4*)gamma;
    const float4* br = (const float4*)beta;
    #pragma unroll
    for (int i = 0; i < 4; ++i) {
        const float4 g  = gr[lane + 64 * i];
        const float4 bt = br[lane + 64 * i];
        ushort4 o;
        o.x = f2bf((v[i].x - mean) * rstd * g.x + bt.x);
        o.y = f2bf((v[i].y - mean) * rstd * g.y + bt.y);
        o.z = f2bf((v[i].z - mean) * rstd * g.z + bt.z);
        o.w = f2bf((v[i].w - mean) * rstd * g.w + bt.w);
        *(ushort4*)(xn + row * E + (lane + 64 * i) * 4) = o;
    }
}

// ---------- Kernel 2: cast W -> bf16 (Wq pre-scaled by log2(e)/8) ----------
__global__ __launch_bounds__(256) void w_cast(const float* __restrict__ Wq,
        const float* __restrict__ Wk, const float* __restrict__ Wv,
        u16* __restrict__ wc) {
    const int row = blockIdx.x;   // 0..191
    const int t = threadIdx.x;
    const float* src = (row < 64)  ? (Wq + (size_t)row * E)
                     : (row < 128) ? (Wk + (size_t)(row - 64) * E)
                                   : (Wv + (size_t)(row - 128) * E);
    const float sc = (row < 64) ? LOG2E_O8 : 1.0f;
    const float4 v = *(const float4*)(src + t * 4);
    ushort4 o;
    o.x = f2bf(v.x * sc); o.y = f2bf(v.y * sc);
    o.z = f2bf(v.z * sc); o.w = f2bf(v.w * sc);
    *(ushort4*)(wc + (size_t)row * E + t * 4) = o;
}

// ---------- Kernel 3: QKV projection, MFMA bf16 ----------
// xn [8192 x 1024] bf16, wc [192 x 1024] bf16 -> qb/kb/vb [8192 x 64] bf16.
// Block: 64 rows x 192 cols; wave w owns col strip 48w..48w+47.
__global__ __launch_bounds__(256) void qkv_mfma(const u16* __restrict__ xn,
        const u16* __restrict__ wc,
        u16* __restrict__ qb, u16* __restrict__ kb, u16* __restrict__ vb) {
    const int row0 = blockIdx.x * 64;
    const int t = threadIdx.x;
    const int w = t >> 6, lane = t & 63;
    const int quad = lane >> 4, r15 = lane & 15;
    __shared__ u16 Xs[64 * 64];    // XOR-swizzled 16B chunks: phys = ch ^ (row&7)
    __shared__ u16 Ws[192 * 64];
    f32x4 acc[4][3] = {};

    for (int kc = 0; kc < E; kc += 64) {
        __syncthreads();
        {   // stage X tile: 64 rows x 64 k
            const int row = t >> 2, ch0 = (t & 3) * 2;
            const uint4* src = (const uint4*)(xn + (size_t)(row0 + row) * E + kc + ch0 * 8);
            const uint4 d0 = src[0], d1 = src[1];
            *(uint4*)&Xs[row * 64 + ((ch0    ) ^ (row & 7)) * 8] = d0;
            *(uint4*)&Xs[row * 64 + ((ch0 + 1) ^ (row & 7)) * 8] = d1;
        }
        #pragma unroll
        for (int i = 0; i < 6; ++i) {   // stage W tile: 192 rows x 64 k
            const int idx = i * 256 + t;
            const int wrow = idx >> 3, ch = idx & 7;
            const uint4 d = *(const uint4*)(wc + (size_t)wrow * E + kc + ch * 8);
            *(uint4*)&Ws[wrow * 64 + (ch ^ (wrow & 7)) * 8] = d;
        }
        __syncthreads();
        #pragma unroll
        for (int kk = 0; kk < 2; ++kk) {
            bf16x8 af[4];
            #pragma unroll
            for (int mt = 0; mt < 4; ++mt) {
                const int xrow = mt * 16 + r15;
                af[mt] = *(const bf16x8*)&Xs[xrow * 64 + ((kk * 4 + quad) ^ (xrow & 7)) * 8];
            }
            #pragma unroll
            for (int j = 0; j < 3; ++j) {
                const int wrow = (w * 3 + j) * 16 + r15;
                const bf16x8 bfr = *(const bf16x8*)&Ws[wrow * 64 + ((kk * 4 + quad) ^ (wrow & 7)) * 8];
                #pragma unroll
                for (int mt = 0; mt < 4; ++mt)
                    acc[mt][j] = __builtin_amdgcn_mfma_f32_16x16x32_bf16(af[mt], bfr, acc[mt][j], 0, 0, 0);
            }
        }
    }
    #pragma unroll
    for (int mt = 0; mt < 4; ++mt)
        #pragma unroll
        for (int j = 0; j < 3; ++j) {
            const int cg  = w * 48 + j * 16 + r15;
            const int sel = cg >> 6;
            const int col = cg & 63;
            u16* base = (sel == 0) ? qb : (sel == 1) ? kb : vb;
            #pragma unroll
            for (int r = 0; r < 4; ++r) {
                const size_t row = (size_t)row0 + mt * 16 + quad * 4 + r;
                base[row * HH + col] = f2bf(acc[mt][j][r]);
            }
        }
}

// ---------- Kernel 4: causal flash attention, MFMA bf16 ----------
// Block = 64 queries (4 waves x 16-row strips); K/V tiles of 64 keys.
// q pre-scaled by log2(e)/8 -> softmax in exp2 domain.
__global__ __launch_bounds__(256) void attn_kernel(const u16* __restrict__ qb,
        const u16* __restrict__ kb, const u16* __restrict__ vb,
        float* __restrict__ out) {
    const int b  = blockIdx.x >> 5;
    const int qt = 31 - (blockIdx.x & 31);   // longest blocks first
    const int q0 = qt << 6;
    const int t = threadIdx.x;
    const int w = t >> 6, lane = t & 63;
    const int quad = lane >> 4, r15 = lane & 15;

    __shared__ u16 Ks[64 * 64];   // [key][h], XOR-swizzled chunks
    __shared__ u16 VT[64 * 64];   // [h][key], XOR-swizzled chunks
    __shared__ u16 Ps[64 * 64];   // [qrow][key], XOR-swizzled chunks (per-wave strips)

    // Q A-frags: rows q0 + w*16 + r15, k = quad*8..+7 (+32)
    const size_t qrow = ((size_t)b * SS + q0 + w * 16 + r15) * HH;
    const bf16x8 qf0 = *(const bf16x8*)(qb + qrow + quad * 8);
    const bf16x8 qf1 = *(const bf16x8*)(qb + qrow + 32 + quad * 8);

    f32x4 o[4] = {};
    float m_[4], l_[4];
    #pragma unroll
    for (int r = 0; r < 4; ++r) { m_[r] = -INFINITY; l_[r] = 0.f; }

    const int ntiles = qt + 1;
    for (int tile = 0; tile < ntiles; ++tile) {
        const int kt = tile << 6;
        __syncthreads();   // prior iteration's reads complete before restaging
        {   // stage K tile [key][h]
            const int row = t >> 2, ch0 = (t & 3) * 2;
            const uint4* src = (const uint4*)(kb + ((size_t)b * SS + kt + row) * HH + ch0 * 8);
            const uint4 d0 = src[0], d1 = src[1];
            *(uint4*)&Ks[row * 64 + ((ch0    ) ^ (row & 7)) * 8] = d0;
            *(uint4*)&Ks[row * 64 + ((ch0 + 1) ^ (row & 7)) * 8] = d1;
        }
        {   // stage V transposed: VT[h][key]
            const int key = t & 63, h0 = (t >> 6) * 16;
            const uint4* src = (const uint4*)(vb + ((size_t)b * SS + kt + key) * HH + h0);
            const uint4 d0 = src[0], d1 = src[1];
            const unsigned int dw[8] = {d0.x, d0.y, d0.z, d0.w, d1.x, d1.y, d1.z, d1.w};
            #pragma unroll
            for (int i = 0; i < 8; ++i) {
                const int ha = h0 + 2 * i, hb = ha + 1;
                VT[ha * 64 + (((key >> 3) ^ (ha & 7)) * 8) + (key & 7)] = (u16)(dw[i] & 0xFFFFu);
                VT[hb * 64 + (((key >> 3) ^ (hb & 7)) * 8) + (key & 7)] = (u16)(dw[i] >> 16);
            }
        }
        __syncthreads();

        // S strip = Q K^T  (16 x 64 per wave)
        f32x4 s[4] = {};
        #pragma unroll
        for (int nt = 0; nt < 4; ++nt) {
            const int krow = nt * 16 + r15;
            const bf16x8 k0 = *(const bf16x8*)&Ks[krow * 64 + ((    quad) ^ (krow & 7)) * 8];
            const bf16x8 k1 = *(const bf16x8*)&Ks[krow * 64 + ((4 + quad) ^ (krow & 7)) * 8];
            s[nt] = __builtin_amdgcn_mfma_f32_16x16x32_bf16(qf0, k0, s[nt], 0, 0, 0);
            s[nt] = __builtin_amdgcn_mfma_f32_16x16x32_bf16(qf1, k1, s[nt], 0, 0, 0);
        }
        if (tile == ntiles - 1) {   // diagonal tile: mask col > row
            #pragma unroll
            for (int nt = 0; nt < 4; ++nt)
                #pragma unroll
                for (int r = 0; r < 4; ++r)
                    if (nt * 16 + r15 > w * 16 + quad * 4 + r) s[nt][r] = -INFINITY;
        }

        // online softmax (exp2 domain; scale already folded into q)
        float p[4][4];
        #pragma unroll
        for (int r = 0; r < 4; ++r) {
            float mx = fmaxf(fmaxf(s[0][r], s[1][r]), fmaxf(s[2][r], s[3][r]));
            mx = fmaxf(mx, __shfl_xor(mx, 1));
            mx = fmaxf(mx, __shfl_xor(mx, 2));
            mx = fmaxf(mx, __shfl_xor(mx, 4));
            mx = fmaxf(mx, __shfl_xor(mx, 8));
            const float mn = fmaxf(m_[r], mx);
            const float alpha = __builtin_amdgcn_exp2f(m_[r] - mn);
            m_[r] = mn;
            float rs = 0.f;
            #pragma unroll
            for (int nt = 0; nt < 4; ++nt) {
                p[nt][r] = __builtin_amdgcn_exp2f(s[nt][r] - mn);
                rs += p[nt][r];
            }
            rs += __shfl_xor(rs, 1); rs += __shfl_xor(rs, 2);
            rs += __shfl_xor(rs, 4); rs += __shfl_xor(rs, 8);
            l_[r] = l_[r] * alpha + rs;
            #pragma unroll
            for (int ht = 0; ht < 4; ++ht) o[ht][r] *= alpha;
        }

        // P strip -> LDS (C-layout write), read back as A-frags (same wave only)
        #pragma unroll
        for (int nt = 0; nt < 4; ++nt)
            #pragma unroll
            for (int r = 0; r < 4; ++r) {
                const int prow = w * 16 + quad * 4 + r;
                const int col  = nt * 16 + r15;
                Ps[prow * 64 + (((col >> 3) ^ (prow & 7)) * 8) + (col & 7)] = f2bf(p[nt][r]);
            }
        const int arow = w * 16 + r15;
        const bf16x8 pf0 = *(const bf16x8*)&Ps[arow * 64 + ((    quad) ^ (arow & 7)) * 8];
        const bf16x8 pf1 = *(const bf16x8*)&Ps[arow * 64 + ((4 + quad) ^ (arow & 7)) * 8];

        // O strip += P V
        #pragma unroll
        for (int ht = 0; ht < 4; ++ht) {
            const int vrow = ht * 16 + r15;
            const bf16x8 v0 = *(const bf16x8*)&VT[vrow * 64 + ((    quad) ^ (vrow & 7)) * 8];
            const bf16x8 v1 = *(const bf16x8*)&VT[vrow * 64 + ((4 + quad) ^ (vrow & 7)) * 8];
            o[ht] = __builtin_amdgcn_mfma_f32_16x16x32_bf16(pf0, v0, o[ht], 0, 0, 0);
            o[ht] = __builtin_amdgcn_mfma_f32_16x16x32_bf16(pf1, v1, o[ht], 0, 0, 0);
        }
    }

    #pragma unroll
    for (int r = 0; r < 4; ++r) {
        const float inv = 1.0f / l_[r];
        const size_t orow = ((size_t)b * SS + q0 + w * 16 + quad * 4 + r) * HH;
        #pragma unroll
        for (int ht = 0; ht < 4; ++ht)
            out[orow + ht * 16 + r15] = o[ht][r] * inv;
    }
}

// ---------- launch ----------
extern "C" void kernel_launch(void* const* d_in, const int* in_sizes, int n_in,
                              void* d_out, int out_size, void* d_ws, size_t ws_size,
                              hipStream_t stream) {
    const float* x     = (const float*)d_in[0];
    const float* gamma = (const float*)d_in[1];
    const float* beta  = (const float*)d_in[2];
    const float* Wq    = (const float*)d_in[3];
    const float* Wk    = (const float*)d_in[4];
    const float* Wv    = (const float*)d_in[5];
    float* out = (float*)d_out;

    // ws: xn bf16 16.78MB | wc bf16 384KB | qb/kb/vb bf16 1MB each
    u16* xn = (u16*)d_ws;
    u16* wc = (u16*)((char*)d_ws + (size_t)BS * E * 2);
    u16* qb = (u16*)((char*)d_ws + (size_t)BS * E * 2 + 393216);
    u16* kb = qb + (size_t)BS * HH;
    u16* vb = kb + (size_t)BS * HH;

    ln_kernel  <<<BS / 4, 256, 0, stream>>>(x, gamma, beta, xn);
    w_cast     <<<192,    256, 0, stream>>>(Wq, Wk, Wv, wc);
    qkv_mfma   <<<BS / 64, 256, 0, stream>>>(xn, wc, qb, kb, vb);
    attn_kernel<<<BS / 64, 256, 0, stream>>>(qb, kb, vb, out);
}

// Round 3
// 144.195 us; speedup vs baseline: 5.3481x; 1.1000x over previous
//
#include <hip/hip_runtime.h>

#define E 1024
#define HH 64
#define BB 4
#define SS 2048
#define BS (BB*SS)   // 8192 rows
#define NSLOT 144    // per-batch split-K slots: sum_{qt=0}^{31} (qt/4 + 1)

typedef unsigned short u16;
typedef short bf16x8 __attribute__((ext_vector_type(8)));
typedef float f32x4 __attribute__((ext_vector_type(4)));

#define LOG2E_O8 0.18033688011112042f   // log2(e)/8 : folds 1/sqrt(64) + exp2 domain

__device__ inline u16 f2bf(float f) {
    unsigned int u = __float_as_uint(f);
    unsigned int r = (u + 0x7FFFu + ((u >> 16) & 1u)) >> 16;   // RNE
    return (u16)r;
}

// ---------- Kernel 1: LayerNorm, wave-per-row, fp32 -> bf16 ----------
__global__ __launch_bounds__(256) void ln_kernel(const float* __restrict__ x,
        const float* __restrict__ gamma, const float* __restrict__ beta,
        u16* __restrict__ xn) {
    const int w = threadIdx.x >> 6, lane = threadIdx.x & 63;
    const size_t row = (size_t)blockIdx.x * 4 + w;
    const float4* xr = (const float4*)(x + row * E);
    float4 v[4];
    #pragma unroll
    for (int i = 0; i < 4; ++i) v[i] = xr[lane + 64 * i];
    float s = 0.f, sq = 0.f;
    #pragma unroll
    for (int i = 0; i < 4; ++i) {
        s  += v[i].x + v[i].y + v[i].z + v[i].w;
        sq += v[i].x*v[i].x + v[i].y*v[i].y + v[i].z*v[i].z + v[i].w*v[i].w;
    }
    #pragma unroll
    for (int off = 32; off > 0; off >>= 1) {
        s  += __shfl_xor(s,  off);
        sq += __shfl_xor(sq, off);
    }
    const float mean = s * (1.0f / E);
    const float var  = sq * (1.0f / E) - mean * mean;
    const float rstd = rsqrtf(var + 1e-5f);
    const float4* gr = (const float4*)gamma;
    const float4* br = (const float4*)beta;
    #pragma unroll
    for (int i = 0; i < 4; ++i) {
        const float4 g  = gr[lane + 64 * i];
        const float4 bt = br[lane + 64 * i];
        ushort4 o;
        o.x = f2bf((v[i].x - mean) * rstd * g.x + bt.x);
        o.y = f2bf((v[i].y - mean) * rstd * g.y + bt.y);
        o.z = f2bf((v[i].z - mean) * rstd * g.z + bt.z);
        o.w = f2bf((v[i].w - mean) * rstd * g.w + bt.w);
        *(ushort4*)(xn + row * E + (lane + 64 * i) * 4) = o;
    }
}

// ---------- Kernel 2: cast W -> bf16 (Wq pre-scaled by log2(e)/8) ----------
__global__ __launch_bounds__(256) void w_cast(const float* __restrict__ Wq,
        const float* __restrict__ Wk, const float* __restrict__ Wv,
        u16* __restrict__ wc) {
    const int row = blockIdx.x;   // 0..191
    const int t = threadIdx.x;
    const float* src = (row < 64)  ? (Wq + (size_t)row * E)
                     : (row < 128) ? (Wk + (size_t)(row - 64) * E)
                                   : (Wv + (size_t)(row - 128) * E);
    const float sc = (row < 64) ? LOG2E_O8 : 1.0f;
    const float4 v = *(const float4*)(src + t * 4);
    ushort4 o;
    o.x = f2bf(v.x * sc); o.y = f2bf(v.y * sc);
    o.z = f2bf(v.z * sc); o.w = f2bf(v.w * sc);
    *(ushort4*)(wc + (size_t)row * E + t * 4) = o;
}

// ---------- Kernel 3: QKV projection, MFMA bf16, 32 rows/block (256 blocks) ----------
// V is written pre-transposed: vt[b][h][key]  (so attention stages it coalesced)
__global__ __launch_bounds__(256) void qkv_mfma(const u16* __restrict__ xn,
        const u16* __restrict__ wc,
        u16* __restrict__ qb, u16* __restrict__ kb, u16* __restrict__ vt) {
    const int row0 = blockIdx.x * 32;
    const int t = threadIdx.x;
    const int w = t >> 6, lane = t & 63;
    const int quad = lane >> 4, r15 = lane & 15;
    __shared__ u16 Xs[32 * 64];    // XOR-swizzled 16B chunks: phys = ch ^ (row&7)
    __shared__ u16 Ws[192 * 64];
    f32x4 acc[2][3] = {};

    for (int kc = 0; kc < E; kc += 64) {
        __syncthreads();
        {   // stage X tile: 32 rows x 64 k
            const int row = t >> 3, ch = t & 7;
            const uint4 d = *(const uint4*)(xn + (size_t)(row0 + row) * E + kc + ch * 8);
            *(uint4*)&Xs[row * 64 + (ch ^ (row & 7)) * 8] = d;
        }
        #pragma unroll
        for (int i = 0; i < 6; ++i) {   // stage W tile: 192 rows x 64 k
            const int idx = i * 256 + t;
            const int wrow = idx >> 3, ch = idx & 7;
            const uint4 d = *(const uint4*)(wc + (size_t)wrow * E + kc + ch * 8);
            *(uint4*)&Ws[wrow * 64 + (ch ^ (wrow & 7)) * 8] = d;
        }
        __syncthreads();
        #pragma unroll
        for (int kk = 0; kk < 2; ++kk) {
            bf16x8 af[2];
            #pragma unroll
            for (int mt = 0; mt < 2; ++mt) {
                const int xrow = mt * 16 + r15;
                af[mt] = *(const bf16x8*)&Xs[xrow * 64 + ((kk * 4 + quad) ^ (xrow & 7)) * 8];
            }
            #pragma unroll
            for (int j = 0; j < 3; ++j) {
                const int wrow = (w * 3 + j) * 16 + r15;
                const bf16x8 bfr = *(const bf16x8*)&Ws[wrow * 64 + ((kk * 4 + quad) ^ (wrow & 7)) * 8];
                #pragma unroll
                for (int mt = 0; mt < 2; ++mt)
                    acc[mt][j] = __builtin_amdgcn_mfma_f32_16x16x32_bf16(af[mt], bfr, acc[mt][j], 0, 0, 0);
            }
        }
    }
    const int b    = row0 >> 11;
    const int key0 = row0 & 2047;
    #pragma unroll
    for (int mt = 0; mt < 2; ++mt)
        #pragma unroll
        for (int j = 0; j < 3; ++j) {
            const int cg  = w * 48 + j * 16 + r15;
            const int sel = cg >> 6;
            const int col = cg & 63;
            if (sel < 2) {
                u16* base = (sel == 0) ? qb : kb;
                #pragma unroll
                for (int r = 0; r < 4; ++r) {
                    const size_t row = (size_t)row0 + mt * 16 + quad * 4 + r;
                    base[row * HH + col] = f2bf(acc[mt][j][r]);
                }
            } else {
                ushort4 pk;
                pk.x = f2bf(acc[mt][j][0]); pk.y = f2bf(acc[mt][j][1]);
                pk.z = f2bf(acc[mt][j][2]); pk.w = f2bf(acc[mt][j][3]);
                *(ushort4*)(vt + (size_t)b * HH * SS + (size_t)col * SS
                               + key0 + mt * 16 + quad * 4) = pk;
            }
        }
}

// ---------- Kernel 4: split-K causal flash attention (partials) ----------
// Block = (b, qt: 64-query tile, c: 256-key chunk). Grid BB*32*8; c > qt/4 exits.
__global__ __launch_bounds__(256) void attn_partial(const u16* __restrict__ qb,
        const u16* __restrict__ kb, const u16* __restrict__ vt,
        float* __restrict__ po, float* __restrict__ pm, float* __restrict__ pl) {
    const int bid = blockIdx.x;
    const int b   = bid >> 8;
    const int rem = bid & 255;
    const int qt  = rem >> 3, c = rem & 7;
    const int a   = qt >> 2;
    if (c > a) return;                       // nc(qt) = a+1 chunks
    const int r_   = qt & 3;
    const int slot = b * NSLOT + 2 * a * (a + 1) + r_ * (a + 1) + c;
    const int q0   = qt << 6;
    const int t = threadIdx.x;
    const int w = t >> 6, lane = t & 63;
    const int quad = lane >> 4, r15 = lane & 15;

    __shared__ u16 Ks[64 * 64];   // [key][h], XOR-swizzled chunks
    __shared__ u16 VT[64 * 64];   // [h][key], XOR-swizzled chunks
    __shared__ u16 Ps[64 * 64];   // [qrow][key], per-wave strips

    const size_t qrow = ((size_t)b * SS + q0 + w * 16 + r15) * HH;
    const bf16x8 qf0 = *(const bf16x8*)(qb + qrow + quad * 8);
    const bf16x8 qf1 = *(const bf16x8*)(qb + qrow + 32 + quad * 8);

    f32x4 o[4] = {};
    float m_[4], l_[4];
    #pragma unroll
    for (int r = 0; r < 4; ++r) { m_[r] = -INFINITY; l_[r] = 0.f; }

    const int t1 = min(c * 4 + 4, qt + 1);
    for (int tile = c * 4; tile < t1; ++tile) {
        const int kt = tile << 6;
        __syncthreads();
        {   // stage K tile [key][h]  (coalesced)
            const int row = t >> 2, ch0 = (t & 3) * 2;
            const uint4* src = (const uint4*)(kb + ((size_t)b * SS + kt + row) * HH + ch0 * 8);
            const uint4 d0 = src[0], d1 = src[1];
            *(uint4*)&Ks[row * 64 + ((ch0    ) ^ (row & 7)) * 8] = d0;
            *(uint4*)&Ks[row * 64 + ((ch0 + 1) ^ (row & 7)) * 8] = d1;
        }
        {   // stage V tile [h][key] straight from pre-transposed vt (coalesced)
            const int h = t >> 2, ch0 = (t & 3) * 2;
            const uint4* src = (const uint4*)(vt + (size_t)b * HH * SS + (size_t)h * SS + kt + ch0 * 8);
            const uint4 d0 = src[0], d1 = src[1];
            *(uint4*)&VT[h * 64 + ((ch0    ) ^ (h & 7)) * 8] = d0;
            *(uint4*)&VT[h * 64 + ((ch0 + 1) ^ (h & 7)) * 8] = d1;
        }
        __syncthreads();

        // S strip = Q K^T (16 x 64 per wave)
        f32x4 s[4] = {};
        #pragma unroll
        for (int nt = 0; nt < 4; ++nt) {
            const int krow = nt * 16 + r15;
            const bf16x8 k0 = *(const bf16x8*)&Ks[krow * 64 + ((    quad) ^ (krow & 7)) * 8];
            const bf16x8 k1 = *(const bf16x8*)&Ks[krow * 64 + ((4 + quad) ^ (krow & 7)) * 8];
            s[nt] = __builtin_amdgcn_mfma_f32_16x16x32_bf16(qf0, k0, s[nt], 0, 0, 0);
            s[nt] = __builtin_amdgcn_mfma_f32_16x16x32_bf16(qf1, k1, s[nt], 0, 0, 0);
        }
        if (tile == qt) {   // diagonal tile: mask key > query
            #pragma unroll
            for (int nt = 0; nt < 4; ++nt)
                #pragma unroll
                for (int r = 0; r < 4; ++r)
                    if (nt * 16 + r15 > w * 16 + quad * 4 + r) s[nt][r] = -INFINITY;
        }

        // online softmax (exp2 domain; scale folded into q)
        float p[4][4];
        #pragma unroll
        for (int r = 0; r < 4; ++r) {
            float mx = fmaxf(fmaxf(s[0][r], s[1][r]), fmaxf(s[2][r], s[3][r]));
            mx = fmaxf(mx, __shfl_xor(mx, 1));
            mx = fmaxf(mx, __shfl_xor(mx, 2));
            mx = fmaxf(mx, __shfl_xor(mx, 4));
            mx = fmaxf(mx, __shfl_xor(mx, 8));
            const float mn = fmaxf(m_[r], mx);
            const float alpha = __builtin_amdgcn_exp2f(m_[r] - mn);
            m_[r] = mn;
            float rs = 0.f;
            #pragma unroll
            for (int nt = 0; nt < 4; ++nt) {
                p[nt][r] = __builtin_amdgcn_exp2f(s[nt][r] - mn);
                rs += p[nt][r];
            }
            rs += __shfl_xor(rs, 1); rs += __shfl_xor(rs, 2);
            rs += __shfl_xor(rs, 4); rs += __shfl_xor(rs, 8);
            l_[r] = l_[r] * alpha + rs;
            #pragma unroll
            for (int ht = 0; ht < 4; ++ht) o[ht][r] *= alpha;
        }

        // P strip -> LDS (C-layout write), read back as A-frags (same wave only)
        #pragma unroll
        for (int nt = 0; nt < 4; ++nt)
            #pragma unroll
            for (int r = 0; r < 4; ++r) {
                const int prow = w * 16 + quad * 4 + r;
                const int col  = nt * 16 + r15;
                Ps[prow * 64 + (((col >> 3) ^ (prow & 7)) * 8) + (col & 7)] = f2bf(p[nt][r]);
            }
        const int arow = w * 16 + r15;
        const bf16x8 pf0 = *(const bf16x8*)&Ps[arow * 64 + ((    quad) ^ (arow & 7)) * 8];
        const bf16x8 pf1 = *(const bf16x8*)&Ps[arow * 64 + ((4 + quad) ^ (arow & 7)) * 8];

        // O strip += P V
        #pragma unroll
        for (int ht = 0; ht < 4; ++ht) {
            const int vrow = ht * 16 + r15;
            const bf16x8 v0 = *(const bf16x8*)&VT[vrow * 64 + ((    quad) ^ (vrow & 7)) * 8];
            const bf16x8 v1 = *(const bf16x8*)&VT[vrow * 64 + ((4 + quad) ^ (vrow & 7)) * 8];
            o[ht] = __builtin_amdgcn_mfma_f32_16x16x32_bf16(pf0, v0, o[ht], 0, 0, 0);
            o[ht] = __builtin_amdgcn_mfma_f32_16x16x32_bf16(pf1, v1, o[ht], 0, 0, 0);
        }
    }

    // write partials: o (fp32, un-normalized), m, l
    #pragma unroll
    for (int r = 0; r < 4; ++r) {
        const int q = w * 16 + quad * 4 + r;
        #pragma unroll
        for (int ht = 0; ht < 4; ++ht)
            po[(size_t)slot * 4096 + q * 64 + ht * 16 + r15] = o[ht][r];
        if (r15 == 0) {
            pm[slot * 64 + q] = m_[r];
            pl[slot * 64 + q] = l_[r];
        }
    }
}

// ---------- Kernel 5: split-K reduce ----------
// Block = (b, qt, 16-query group). Thread = (h, 4 queries).
__global__ __launch_bounds__(256) void attn_reduce(const float* __restrict__ po,
        const float* __restrict__ pm, const float* __restrict__ pl,
        float* __restrict__ out) {
    const int bid = blockIdx.x;            // 512
    const int b = bid >> 7, rem = bid & 127;
    const int qt = rem >> 2, qq = rem & 3;
    const int a = qt >> 2, r_ = qt & 3;
    const int nc = a + 1;
    const int sbase = b * NSLOT + 2 * a * (a + 1) + r_ * (a + 1);
    const int t = threadIdx.x;
    const int h = t & 63, qr = t >> 6;
    #pragma unroll
    for (int i = 0; i < 4; ++i) {
        const int q = qq * 16 + qr * 4 + i;   // query within 64-tile
        float mstar = -INFINITY;
        for (int cidx = 0; cidx < nc; ++cidx)
            mstar = fmaxf(mstar, pm[(sbase + cidx) * 64 + q]);
        float osum = 0.f, lsum = 0.f;
        for (int cidx = 0; cidx < nc; ++cidx) {
            const float sc = __builtin_amdgcn_exp2f(pm[(sbase + cidx) * 64 + q] - mstar);
            osum += sc * po[(size_t)(sbase + cidx) * 4096 + q * 64 + h];
            lsum += sc * pl[(sbase + cidx) * 64 + q];
        }
        out[((size_t)b * SS + (qt << 6) + q) * HH + h] = osum / lsum;
    }
}

// ---------- launch ----------
extern "C" void kernel_launch(void* const* d_in, const int* in_sizes, int n_in,
                              void* d_out, int out_size, void* d_ws, size_t ws_size,
                              hipStream_t stream) {
    const float* x     = (const float*)d_in[0];
    const float* gamma = (const float*)d_in[1];
    const float* beta  = (const float*)d_in[2];
    const float* Wq    = (const float*)d_in[3];
    const float* Wk    = (const float*)d_in[4];
    const float* Wv    = (const float*)d_in[5];
    float* out = (float*)d_out;

    // ws: [xn bf16 16.78MB | wc 384KB | qb 1MB | kb 1MB | vt 1MB]  (20.3MB total)
    // split-K partials (9.73MB) alias the xn region (xn dead after qkv_mfma).
    u16* xn = (u16*)d_ws;
    u16* wc = (u16*)((char*)d_ws + (size_t)BS * E * 2);
    u16* qb = (u16*)((char*)d_ws + (size_t)BS * E * 2 + 393216);
    u16* kb = qb + (size_t)BS * HH;
    u16* vt = kb + (size_t)BS * HH;
    float* po = (float*)d_ws;                       // 576 * 4096 floats
    float* pm = po + (size_t)BB * NSLOT * 4096;     // 576 * 64
    float* pl = pm + (size_t)BB * NSLOT * 64;       // 576 * 64

    ln_kernel   <<<BS / 4,     256, 0, stream>>>(x, gamma, beta, xn);
    w_cast      <<<192,        256, 0, stream>>>(Wq, Wk, Wv, wc);
    qkv_mfma    <<<BS / 32,    256, 0, stream>>>(xn, wc, qb, kb, vt);
    attn_partial<<<BB * 32 * 8, 256, 0, stream>>>(qb, kb, vt, po, pm, pl);
    attn_reduce <<<BB * 32 * 4, 256, 0, stream>>>(po, pm, pl, out);
}